// Round 1
// baseline (739.844 us; speedup 1.0000x reference)
//
#include <hip/hip_runtime.h>
#include <cstdint>
#include <cstddef>

typedef unsigned short u16;
typedef __attribute__((ext_vector_type(8))) __bf16 bf16x8;
typedef __attribute__((ext_vector_type(4))) float f32x4;
typedef __attribute__((ext_vector_type(8))) u16 u16x8;
typedef __attribute__((ext_vector_type(4))) u16 u16x4;

#define MTOT   38400   // B*T*N rows
#define DMODEL 256
#define NQKV   768
#define NN     400
#define NBT    96      // B*T
#define SCALE  0.17677669529663687f   // 1/sqrt(32)

__device__ __forceinline__ u16 f2b(float f){
  __bf16 b = (__bf16)f;
  return __builtin_bit_cast(u16, b);
}

__device__ __forceinline__ void g2l16(const void* g, void* l){
  __builtin_amdgcn_global_load_lds(
      (const __attribute__((address_space(1))) unsigned int*)g,
      (__attribute__((address_space(3))) unsigned int*)l,
      16, 0, 0);
}

// ---------------- prep: cast x -> bf16 ----------------
__global__ __launch_bounds__(256) void cast_x_kernel(const float* __restrict__ x,
                                                     u16* __restrict__ xb, int n8){
  int i = blockIdx.x * 256 + threadIdx.x;
  if (i >= n8) return;
  const f32x4* xp = (const f32x4*)x;
  f32x4 a = xp[2*i], b = xp[2*i+1];
  u16x8 o;
  o[0]=f2b(a[0]); o[1]=f2b(a[1]); o[2]=f2b(a[2]); o[3]=f2b(a[3]);
  o[4]=f2b(b[0]); o[5]=f2b(b[1]); o[6]=f2b(b[2]); o[7]=f2b(b[3]);
  ((u16x8*)xb)[i] = o;
}

// ---------------- prep: pack Wq/Wk/Wv -> bf16 [768][256], bias -> f32[768] ----------------
__global__ __launch_bounds__(256) void prep_w_kernel(
    const float* __restrict__ wq, const float* __restrict__ wk, const float* __restrict__ wv,
    const float* __restrict__ bq, const float* __restrict__ bk, const float* __restrict__ bv,
    u16* __restrict__ wqkv, float* __restrict__ bqkv){
  int i = blockIdx.x * 256 + threadIdx.x;      // 49152 threads, 4 elems each
  int g = i >> 14;                              // 16384 float4 per matrix
  int rem = (i & 16383) * 4;
  const float* w = (g == 0) ? wq : ((g == 1) ? wk : wv);
  f32x4 v = *(const f32x4*)(w + rem);
  u16x4 o; o[0]=f2b(v[0]); o[1]=f2b(v[1]); o[2]=f2b(v[2]); o[3]=f2b(v[3]);
  *(u16x4*)(wqkv + (size_t)i*4) = o;
  if (i < NQKV) bqkv[i] = (i < 256) ? bq[i] : ((i < 512) ? bk[i-256] : bv[i-512]);
}

// ---------------- QKV GEMM: qkv[m][n] = xb[m][:] . wqkv[n][:] + bqkv[n] (bf16 out) ----------------
__global__ __launch_bounds__(256,2) void gemm_qkv_kernel(
    const u16* __restrict__ xb, const u16* __restrict__ wqkv,
    const float* __restrict__ bqkv, u16* __restrict__ qkv){
  __shared__ u16 a_lds[128*64];
  __shared__ u16 b_lds[128*64];
  const int tid = threadIdx.x, lane = tid & 63, wave = tid >> 6;
  const int bn = blockIdx.x % 6, bm = blockIdx.x / 6;
  const int m0 = bm*128, n0 = bn*128;
  const int wm = (wave>>1)*64, wn = (wave&1)*64;
  const int lr = lane & 15, lk = lane >> 4;
  f32x4 acc[4][4] = {};
  for (int k0 = 0; k0 < 256; k0 += 64){
    #pragma unroll
    for (int i = 0; i < 4; ++i){
      int off  = (wave*4 + i)*1024 + lane*16;   // byte offset in 16KB tile
      int row  = off >> 7;                      // /128B per row (64 bf16)
      int colb = off & 127;
      int scolb = colb ^ ((row & 7) << 4);      // inverse-swizzled SOURCE (rule #21)
      g2l16(xb   + (size_t)(m0+row)*256 + k0 + (scolb>>1), (char*)a_lds + (size_t)(wave*4+i)*1024);
      g2l16(wqkv + (size_t)(n0+row)*256 + k0 + (scolb>>1), (char*)b_lds + (size_t)(wave*4+i)*1024);
    }
    __syncthreads();
    #pragma unroll
    for (int sub = 0; sub < 2; ++sub){
      bf16x8 af[4], bfr[4];
      #pragma unroll
      for (int i = 0; i < 4; ++i){
        int ra = wm + i*16 + lr;
        af[i]  = *(const bf16x8*)((const char*)a_lds + ra*128 + ((sub*64 + lk*16) ^ ((ra&7)<<4)));
        int rb = wn + i*16 + lr;
        bfr[i] = *(const bf16x8*)((const char*)b_lds + rb*128 + ((sub*64 + lk*16) ^ ((rb&7)<<4)));
      }
      #pragma unroll
      for (int i = 0; i < 4; ++i)
        #pragma unroll
        for (int j = 0; j < 4; ++j)
          acc[i][j] = __builtin_amdgcn_mfma_f32_16x16x32_bf16(af[i], bfr[j], acc[i][j], 0, 0, 0);
    }
    __syncthreads();
  }
  #pragma unroll
  for (int j = 0; j < 4; ++j){
    int n = n0 + wn + j*16 + lr;               // D col = lane&15
    float bias = bqkv[n];
    #pragma unroll
    for (int i = 0; i < 4; ++i){
      int mb = m0 + wm + i*16 + lk*4;          // D row = (lane>>4)*4 + r
      #pragma unroll
      for (int r = 0; r < 4; ++r)
        qkv[(size_t)(mb + r)*NQKV + n] = f2b(acc[i][j][r] + bias);
    }
  }
}

// ---------------- attention: per (b,t,h) block ----------------
#define K_STRIDE 40            // elems (80B rows -> 2-way bank alias, free)
#define VT_STRIDE 424          // elems (848B rows)
#define ATTN_LDS (NN*K_STRIDE*2 + 32*VT_STRIDE*2 + 4*16*VT_STRIDE*2)  // 113408 B

__global__ __launch_bounds__(256,1) void attn_kernel(
    const u16* __restrict__ qkv, const float* __restrict__ adj, float* __restrict__ hout){
  extern __shared__ char smem[];
  u16* k_lds = (u16*)smem;                                  // [400][40]
  u16* vT    = (u16*)(smem + NN*K_STRIDE*2);                // [32][424] (k-cols 400..415 zeroed)
  u16* p_all = (u16*)(smem + NN*K_STRIDE*2 + 32*VT_STRIDE*2); // [4 waves][16][424]
  const int tid = threadIdx.x, lane = tid & 63, wave = tid >> 6;
  const int h = blockIdx.x / NBT, bt = blockIdx.x % NBT;    // bid%8 == bt%8 -> same-bt heads share an XCD
  const int lr = lane & 15, lk = lane >> 4;
  const u16* qkvbt = qkv + (size_t)bt*NN*NQKV + h*32;

  // stage K [400][32] bf16 into padded LDS
  for (int c = tid; c < 1600; c += 256){
    int row = c >> 2, cc = (c & 3)*8;
    *(u16x8*)(k_lds + row*K_STRIDE + cc) = *(const u16x8*)(qkvbt + 256 + (size_t)row*NQKV + cc);
  }
  // stage V transposed: vT[vdim][k]
  for (int c = tid; c < 1600; c += 256){
    int row = c >> 2, cc = (c & 3)*8;
    u16x8 v = *(const u16x8*)(qkvbt + 512 + (size_t)row*NQKV + cc);
    #pragma unroll
    for (int e = 0; e < 8; ++e) vT[(size_t)(cc+e)*VT_STRIDE + row] = v[e];
  }
  // zero pad k-cols 400..423 of vT
  for (int i = tid; i < 32*24; i += 256) vT[(size_t)(i/24)*VT_STRIDE + 400 + (i%24)] = 0;
  // zero pad of this wave's P buffer
  u16* pw = p_all + (size_t)wave*16*VT_STRIDE;
  for (int i = lane; i < 16*24; i += 64) pw[(size_t)(i/24)*VT_STRIDE + 400 + (i%24)] = 0;
  __syncthreads();

  const float* adjbt = adj + (size_t)bt*NN*NN;
  const f32x4 z = {0.f, 0.f, 0.f, 0.f};
  for (int t25 = wave; t25 < 25; t25 += 4){
    const int q0 = t25*16;
    // Q A-frag straight from global: A[row=lane&15][k=(lane>>4)*8+e]
    bf16x8 qf = *(const bf16x8*)(qkvbt + (size_t)(q0 + lr)*NQKV + lk*8);
    f32x4 s[25];
    #pragma unroll
    for (int kt = 0; kt < 25; ++kt){
      bf16x8 kf = *(const bf16x8*)(k_lds + (size_t)(kt*16 + lr)*K_STRIDE + lk*8);
      s[kt] = __builtin_amdgcn_mfma_f32_16x16x32_bf16(qf, kf, z, 0, 0, 0);
    }
    // scale * adj, row max
    float mx[4] = {-1e30f, -1e30f, -1e30f, -1e30f};
    #pragma unroll
    for (int kt = 0; kt < 25; ++kt){
      #pragma unroll
      for (int r = 0; r < 4; ++r){
        float a = adjbt[(size_t)(q0 + lk*4 + r)*NN + kt*16 + lr];
        float v = s[kt][r] * (a * SCALE);
        s[kt][r] = v;
        mx[r] = fmaxf(mx[r], v);
      }
    }
    #pragma unroll
    for (int r = 0; r < 4; ++r){
      float m = mx[r];
      m = fmaxf(m, __shfl_xor(m, 1)); m = fmaxf(m, __shfl_xor(m, 2));
      m = fmaxf(m, __shfl_xor(m, 4)); m = fmaxf(m, __shfl_xor(m, 8));
      mx[r] = m;
    }
    float sm[4] = {0.f, 0.f, 0.f, 0.f};
    #pragma unroll
    for (int kt = 0; kt < 25; ++kt){
      #pragma unroll
      for (int r = 0; r < 4; ++r){
        float e = __expf(s[kt][r] - mx[r]);
        s[kt][r] = e; sm[r] += e;
      }
    }
    #pragma unroll
    for (int r = 0; r < 4; ++r){
      float t = sm[r];
      t += __shfl_xor(t, 1); t += __shfl_xor(t, 2);
      t += __shfl_xor(t, 4); t += __shfl_xor(t, 8);
      sm[r] = 1.0f / t;
    }
    // P -> per-wave LDS (layout fix for PV A-frags)
    #pragma unroll
    for (int r = 0; r < 4; ++r){
      int prow = lk*4 + r;
      #pragma unroll
      for (int kt = 0; kt < 25; ++kt)
        pw[(size_t)prow*VT_STRIDE + kt*16 + lr] = f2b(s[kt][r] * sm[r]);
    }
    // PV: O[16][32] = P[16][416] @ V[416][32]
    f32x4 o0 = z, o1 = z;
    #pragma unroll
    for (int ch = 0; ch < 13; ++ch){
      bf16x8 pf = *(const bf16x8*)(pw + (size_t)lr*VT_STRIDE + ch*32 + lk*8);
      bf16x8 v0 = *(const bf16x8*)(vT + (size_t)lr*VT_STRIDE + ch*32 + lk*8);
      bf16x8 v1 = *(const bf16x8*)(vT + (size_t)(16 + lr)*VT_STRIDE + ch*32 + lk*8);
      o0 = __builtin_amdgcn_mfma_f32_16x16x32_bf16(pf, v0, o0, 0, 0, 0);
      o1 = __builtin_amdgcn_mfma_f32_16x16x32_bf16(pf, v1, o1, 0, 0, 0);
    }
    float* orow = hout + (size_t)(bt*NN + q0)*DMODEL + h*32;
    #pragma unroll
    for (int r = 0; r < 4; ++r){
      orow[(lk*4 + r)*DMODEL + lr]      = o0[r];
      orow[(lk*4 + r)*DMODEL + 16 + lr] = o1[r];
    }
  }
}

// ---------------- residual + LayerNorm ----------------
__global__ __launch_bounds__(256) void resid_ln_kernel(
    const float* __restrict__ hbuf, const float* __restrict__ x,
    const float* __restrict__ gamma, const float* __restrict__ beta,
    float* __restrict__ out){
  const int wave = threadIdx.x >> 6, lane = threadIdx.x & 63;
  const int row = blockIdx.x*4 + wave;
  const f32x4* hp = (const f32x4*)(hbuf + (size_t)row*DMODEL);
  const f32x4* xp = (const f32x4*)(x    + (size_t)row*DMODEL);
  f32x4 y = hp[lane] + xp[lane];
  float s = y[0] + y[1] + y[2] + y[3];
  s += __shfl_xor(s, 1);  s += __shfl_xor(s, 2);  s += __shfl_xor(s, 4);
  s += __shfl_xor(s, 8);  s += __shfl_xor(s, 16); s += __shfl_xor(s, 32);
  float mu = s * (1.0f/256.0f);
  f32x4 d = y - mu;
  float vs = d[0]*d[0] + d[1]*d[1] + d[2]*d[2] + d[3]*d[3];
  vs += __shfl_xor(vs, 1);  vs += __shfl_xor(vs, 2);  vs += __shfl_xor(vs, 4);
  vs += __shfl_xor(vs, 8);  vs += __shfl_xor(vs, 16); vs += __shfl_xor(vs, 32);
  float rs = rsqrtf(vs * (1.0f/256.0f) + 1e-5f);
  f32x4 g = ((const f32x4*)gamma)[lane];
  f32x4 b = ((const f32x4*)beta)[lane];
  f32x4 o = d*rs*g + b;
  ((f32x4*)(out + (size_t)row*DMODEL))[lane] = o;
}

// ---------------- launch ----------------
extern "C" void kernel_launch(void* const* d_in, const int* in_sizes, int n_in,
                              void* d_out, int out_size, void* d_ws, size_t ws_size,
                              hipStream_t stream){
  const float* x     = (const float*)d_in[0];
  const float* adj   = (const float*)d_in[1];
  const float* Wq    = (const float*)d_in[2];
  const float* bq    = (const float*)d_in[3];
  const float* Wk    = (const float*)d_in[4];
  const float* bk    = (const float*)d_in[5];
  const float* Wv    = (const float*)d_in[6];
  const float* bv    = (const float*)d_in[7];
  const float* gamma = (const float*)d_in[8];
  const float* beta  = (const float*)d_in[9];
  float* out = (float*)d_out;
  char* ws = (char*)d_ws;

  // workspace carve (bytes)
  u16*   xb   = (u16*)  (ws + 0);            // 38400*256*2   = 19,660,800
  u16*   wqkv = (u16*)  (ws + 19660800);     // 768*256*2     = 393,216
  float* bqkv = (float*)(ws + 20054016);     // 768*4         = 3,072
  u16*   qkv  = (u16*)  (ws + 20057088);     // 38400*768*2   = 58,982,400
  float* hbuf = (float*)(ws + 79039488);     // 38400*256*4   = 39,321,600  -> ends 118,361,088

  cast_x_kernel<<<4800, 256, 0, stream>>>(x, xb, 9830400/8);
  prep_w_kernel<<<192, 256, 0, stream>>>(Wq, Wk, Wv, bq, bk, bv, wqkv, bqkv);
  gemm_qkv_kernel<<<1800, 256, 0, stream>>>(xb, wqkv, bqkv, qkv);
  (void)hipFuncSetAttribute((const void*)attn_kernel,
                            hipFuncAttributeMaxDynamicSharedMemorySize, ATTN_LDS);
  attn_kernel<<<768, 256, ATTN_LDS, stream>>>(qkv, adj, hbuf);
  resid_ln_kernel<<<9600, 256, 0, stream>>>(hbuf, x, gamma, beta, out);
}

// Round 3
// 251.764 us; speedup vs baseline: 2.9386x; 2.9386x over previous
//
#include <hip/hip_runtime.h>
#include <cstdint>
#include <cstddef>

typedef unsigned short u16;
typedef __attribute__((ext_vector_type(8))) __bf16 bf16x8;
typedef __attribute__((ext_vector_type(4))) float f32x4;
typedef __attribute__((ext_vector_type(8))) u16 u16x8;
typedef __attribute__((ext_vector_type(4))) u16 u16x4;

#define MTOT   38400   // B*T*N rows
#define DMODEL 256
#define NQKV   768
#define NN     400
#define NBT    96      // B*T
#define SCALE  0.17677669529663687f   // 1/sqrt(32), folded into Wq/bq at prep

__device__ __forceinline__ u16 f2b(float f){
  __bf16 b = (__bf16)f;
  return __builtin_bit_cast(u16, b);
}

__device__ __forceinline__ void g2l16(const void* g, void* l){
  __builtin_amdgcn_global_load_lds(
      (const __attribute__((address_space(1))) unsigned int*)g,
      (__attribute__((address_space(3))) unsigned int*)l,
      16, 0, 0);
}

// ---------------- prep: cast x -> bf16 ----------------
__global__ __launch_bounds__(256) void cast_x_kernel(const float* __restrict__ x,
                                                     u16* __restrict__ xb, int n8){
  int i = blockIdx.x * 256 + threadIdx.x;
  if (i >= n8) return;
  const f32x4* xp = (const f32x4*)x;
  f32x4 a = xp[2*i], b = xp[2*i+1];
  u16x8 o;
  o[0]=f2b(a[0]); o[1]=f2b(a[1]); o[2]=f2b(a[2]); o[3]=f2b(a[3]);
  o[4]=f2b(b[0]); o[5]=f2b(b[1]); o[6]=f2b(b[2]); o[7]=f2b(b[3]);
  ((u16x8*)xb)[i] = o;
}

// ---------------- prep: pack Wq*S/Wk/Wv -> bf16 [768][256], bias -> f32[768] ----------------
__global__ __launch_bounds__(256) void prep_w_kernel(
    const float* __restrict__ wq, const float* __restrict__ wk, const float* __restrict__ wv,
    const float* __restrict__ bq, const float* __restrict__ bk, const float* __restrict__ bv,
    u16* __restrict__ wqkv, float* __restrict__ bqkv){
  int i = blockIdx.x * 256 + threadIdx.x;      // 49152 threads, 4 elems each
  int g = i >> 14;                              // 16384 float4 per matrix
  int rem = (i & 16383) * 4;
  const float* w = (g == 0) ? wq : ((g == 1) ? wk : wv);
  float sc = (g == 0) ? SCALE : 1.0f;           // fold 1/sqrt(hd) into Q projection
  f32x4 v = *(const f32x4*)(w + rem);
  u16x4 o; o[0]=f2b(v[0]*sc); o[1]=f2b(v[1]*sc); o[2]=f2b(v[2]*sc); o[3]=f2b(v[3]*sc);
  *(u16x4*)(wqkv + (size_t)i*4) = o;
  if (i < NQKV) bqkv[i] = (i < 256) ? bq[i]*SCALE : ((i < 512) ? bk[i-256] : bv[i-512]);
}

// ---------------- QKV GEMM: qkv[m][n] = xb[m][:] . wqkv[n][:] + bqkv[n] (bf16 out) ----------------
__global__ __launch_bounds__(256,2) void gemm_qkv_kernel(
    const u16* __restrict__ xb, const u16* __restrict__ wqkv,
    const float* __restrict__ bqkv, u16* __restrict__ qkv){
  __shared__ u16 a_lds[128*64];
  __shared__ u16 b_lds[128*64];
  const int tid = threadIdx.x, lane = tid & 63, wave = tid >> 6;
  const int bn = blockIdx.x % 6, bm = blockIdx.x / 6;
  const int m0 = bm*128, n0 = bn*128;
  const int wm = (wave>>1)*64, wn = (wave&1)*64;
  const int lr = lane & 15, lk = lane >> 4;
  f32x4 acc[4][4] = {};
  for (int k0 = 0; k0 < 256; k0 += 64){
    #pragma unroll
    for (int i = 0; i < 4; ++i){
      int off  = (wave*4 + i)*1024 + lane*16;   // byte offset in 16KB tile
      int row  = off >> 7;                      // /128B per row (64 bf16)
      int colb = off & 127;
      int scolb = colb ^ ((row & 7) << 4);      // inverse-swizzled SOURCE (rule #21)
      g2l16(xb   + (size_t)(m0+row)*256 + k0 + (scolb>>1), (char*)a_lds + (size_t)(wave*4+i)*1024);
      g2l16(wqkv + (size_t)(n0+row)*256 + k0 + (scolb>>1), (char*)b_lds + (size_t)(wave*4+i)*1024);
    }
    __syncthreads();
    #pragma unroll
    for (int sub = 0; sub < 2; ++sub){
      bf16x8 af[4], bfr[4];
      #pragma unroll
      for (int i = 0; i < 4; ++i){
        int ra = wm + i*16 + lr;
        af[i]  = *(const bf16x8*)((const char*)a_lds + ra*128 + ((sub*64 + lk*16) ^ ((ra&7)<<4)));
        int rb = wn + i*16 + lr;
        bfr[i] = *(const bf16x8*)((const char*)b_lds + rb*128 + ((sub*64 + lk*16) ^ ((rb&7)<<4)));
      }
      #pragma unroll
      for (int i = 0; i < 4; ++i)
        #pragma unroll
        for (int j = 0; j < 4; ++j)
          acc[i][j] = __builtin_amdgcn_mfma_f32_16x16x32_bf16(af[i], bfr[j], acc[i][j], 0, 0, 0);
    }
    __syncthreads();
  }
  #pragma unroll
  for (int j = 0; j < 4; ++j){
    int n = n0 + wn + j*16 + lr;               // D col = lane&15
    float bias = bqkv[n];
    #pragma unroll
    for (int i = 0; i < 4; ++i){
      int mb = m0 + wm + i*16 + lk*4;          // D row = (lane>>4)*4 + r
      #pragma unroll
      for (int r = 0; r < 4; ++r)
        qkv[(size_t)(mb + r)*NQKV + n] = f2b(acc[i][j][r] + bias);
    }
  }
}

// ---------------- attention: per (b,t,h) block, swapped-QK layout ----------------
// LDS: K [400][32] bf16 XOR-swizzled (25600 B)
//      vT [32][424] bf16 (27136 B), cols 400..415 zeroed
//      P  [4 waves][2 bufs][16][40] bf16 (10240 B)      total 62976 B -> 2 blocks/CU
#define VT_STRIDE 424
#define PW_STRIDE 40
#define K_BYTES   25600
#define VT_BYTES  27136

__global__ __launch_bounds__(256,2) void attn_kernel(
    const u16* __restrict__ qkv, const float* __restrict__ adj, float* __restrict__ hout){
  __shared__ __align__(16) char smem[62976];
  u16* vT    = (u16*)(smem + K_BYTES);
  u16* p_all = (u16*)(smem + K_BYTES + VT_BYTES);
  const int tid = threadIdx.x, lane = tid & 63, wave = tid >> 6;
  const int h = blockIdx.x / NBT, bt = blockIdx.x % NBT;   // bid%8 == bt%8 -> same-bt heads share an XCD
  const int lq = lane & 15, lk = lane >> 4;
  const u16* qkvbt = qkv + (size_t)bt*NN*NQKV + h*32;

  // ---- stage K [400][32] via global_load_lds (16B), pre-swizzled source, linear LDS dest
  {
    const u16* kbase = qkvbt + 256;
    int rsub = lane >> 2;                 // 0..15
    int colb = (lane & 3) * 16;           // 0,16,32,48 bytes
    for (int c = wave; c < 25; c += 4){
      int row  = c*16 + rsub;
      int scol = colb ^ ((row & 3) << 4); // inverse swizzle on SOURCE
      g2l16(kbase + (size_t)row*NQKV + (scol >> 1), smem + c*1024);
    }
  }
  // ---- stage V transposed: vT[d][k]
  for (int c = tid; c < 1600; c += 256){
    int row = c >> 2, cc = (c & 3)*8;
    u16x8 v = *(const u16x8*)(qkvbt + 512 + (size_t)row*NQKV + cc);
    #pragma unroll
    for (int e = 0; e < 8; ++e) vT[(cc+e)*VT_STRIDE + row] = v[e];
  }
  // zero vT k-cols 400..415 (read by window 12)
  for (int i = tid; i < 32*16; i += 256) vT[(i>>4)*VT_STRIDE + 400 + (i&15)] = 0;
  __syncthreads();

  const float* adjbt = adj + (size_t)bt*NN*NN;
  u16* pw = p_all + wave*(2*16*PW_STRIDE);
  const f32x4 z = {0.f, 0.f, 0.f, 0.f};

  for (int t25 = wave; t25 < 25; t25 += 4){
    const int q0 = t25*16;
    // Q B-frag from global: B[row=lane&15 = q][k=(lane>>4)*8+e]
    bf16x8 qf = *(const bf16x8*)(qkvbt + (size_t)(q0 + lq)*NQKV + lk*8);
    // QK^T swapped: s[kt] holds S[q = lq][k = kt*16 + lk*4 + r]
    f32x4 s[25];
    #pragma unroll
    for (int kt = 0; kt < 25; ++kt){
      int row = kt*16 + lq;
      bf16x8 kf = *(const bf16x8*)((const char*)smem + row*64 + ((lk*16) ^ ((row & 3) << 4)));
      s[kt] = __builtin_amdgcn_mfma_f32_16x16x32_bf16(kf, qf, z, 0, 0, 0);
    }
    // adj mask: contiguous f32x4 per lane (coalesced)
    const float* arow = adjbt + (size_t)(q0 + lq)*NN + lk*4;
    #pragma unroll
    for (int kt = 0; kt < 25; ++kt){
      f32x4 a = *(const f32x4*)(arow + kt*16);
      s[kt] *= a;
    }
    // row max (lane-local tree + 2 shuffles across lk groups)
    f32x4 mv = s[0];
    #pragma unroll
    for (int kt = 1; kt < 25; ++kt){
      mv[0]=fmaxf(mv[0],s[kt][0]); mv[1]=fmaxf(mv[1],s[kt][1]);
      mv[2]=fmaxf(mv[2],s[kt][2]); mv[3]=fmaxf(mv[3],s[kt][3]);
    }
    float m = fmaxf(fmaxf(mv[0],mv[1]), fmaxf(mv[2],mv[3]));
    m = fmaxf(m, __shfl_xor(m, 16)); m = fmaxf(m, __shfl_xor(m, 32));
    // exp + sum (4 independent chains)
    f32x4 sv = z;
    #pragma unroll
    for (int kt = 0; kt < 25; ++kt){
      #pragma unroll
      for (int j = 0; j < 4; ++j){
        float e = __expf(s[kt][j] - m);
        s[kt][j] = e; sv[j] += e;
      }
    }
    float sum = (sv[0]+sv[1]) + (sv[2]+sv[3]);
    sum += __shfl_xor(sum, 16); sum += __shfl_xor(sum, 32);
    float inv = 1.0f / sum;
    // PV over 13 windows of 32 k; P round-trips a tiny double-buffered LDS chunk
    f32x4 o0 = z, o1 = z;
    #pragma unroll
    for (int w = 0; w < 13; ++w){
      u16* buf = pw + (w & 1)*(16*PW_STRIDE);
      u16x4 pk0, pk1;
      #pragma unroll
      for (int j = 0; j < 4; ++j) pk0[j] = f2b(s[2*w][j]);
      if (w < 12){
        #pragma unroll
        for (int j = 0; j < 4; ++j) pk1[j] = f2b(s[2*w+1][j]);
      } else {
        pk1[0]=0; pk1[1]=0; pk1[2]=0; pk1[3]=0;
      }
      *(u16x4*)(buf + lq*PW_STRIDE + lk*4)      = pk0;
      *(u16x4*)(buf + lq*PW_STRIDE + 16 + lk*4) = pk1;
      bf16x8 pf = *(const bf16x8*)((const char*)buf + lq*80 + lk*16);
      bf16x8 v0 = *(const bf16x8*)((const char*)vT + (size_t)lq*848      + w*64 + lk*16);
      bf16x8 v1 = *(const bf16x8*)((const char*)vT + (size_t)(16+lq)*848 + w*64 + lk*16);
      o0 = __builtin_amdgcn_mfma_f32_16x16x32_bf16(pf, v0, o0, 0, 0, 0);
      o1 = __builtin_amdgcn_mfma_f32_16x16x32_bf16(pf, v1, o1, 0, 0, 0);
    }
    // epilogue: O[q = lk*4+r][d = lq (+16)], scale by 1/sum of that q-row
    float* orow = hout + (size_t)(bt*NN + q0)*DMODEL + h*32;
    #pragma unroll
    for (int r = 0; r < 4; ++r){
      float invq = __shfl(inv, lk*4 + r);
      orow[(lk*4 + r)*DMODEL + lq]      = o0[r]*invq;
      orow[(lk*4 + r)*DMODEL + 16 + lq] = o1[r]*invq;
    }
  }
}

// ---------------- residual + LayerNorm ----------------
__global__ __launch_bounds__(256) void resid_ln_kernel(
    const float* __restrict__ hbuf, const float* __restrict__ x,
    const float* __restrict__ gamma, const float* __restrict__ beta,
    float* __restrict__ out){
  const int wave = threadIdx.x >> 6, lane = threadIdx.x & 63;
  const int row = blockIdx.x*4 + wave;
  const f32x4* hp = (const f32x4*)(hbuf + (size_t)row*DMODEL);
  const f32x4* xp = (const f32x4*)(x    + (size_t)row*DMODEL);
  f32x4 y = hp[lane] + xp[lane];
  float s = y[0] + y[1] + y[2] + y[3];
  s += __shfl_xor(s, 1);  s += __shfl_xor(s, 2);  s += __shfl_xor(s, 4);
  s += __shfl_xor(s, 8);  s += __shfl_xor(s, 16); s += __shfl_xor(s, 32);
  float mu = s * (1.0f/256.0f);
  f32x4 d = y - mu;
  float vs = d[0]*d[0] + d[1]*d[1] + d[2]*d[2] + d[3]*d[3];
  vs += __shfl_xor(vs, 1);  vs += __shfl_xor(vs, 2);  vs += __shfl_xor(vs, 4);
  vs += __shfl_xor(vs, 8);  vs += __shfl_xor(vs, 16); vs += __shfl_xor(vs, 32);
  float rs = rsqrtf(vs * (1.0f/256.0f) + 1e-5f);
  f32x4 g = ((const f32x4*)gamma)[lane];
  f32x4 b = ((const f32x4*)beta)[lane];
  f32x4 o = d*rs*g + b;
  ((f32x4*)(out + (size_t)row*DMODEL))[lane] = o;
}

// ---------------- launch ----------------
extern "C" void kernel_launch(void* const* d_in, const int* in_sizes, int n_in,
                              void* d_out, int out_size, void* d_ws, size_t ws_size,
                              hipStream_t stream){
  const float* x     = (const float*)d_in[0];
  const float* adj   = (const float*)d_in[1];
  const float* Wq    = (const float*)d_in[2];
  const float* bq    = (const float*)d_in[3];
  const float* Wk    = (const float*)d_in[4];
  const float* bk    = (const float*)d_in[5];
  const float* Wv    = (const float*)d_in[6];
  const float* bv    = (const float*)d_in[7];
  const float* gamma = (const float*)d_in[8];
  const float* beta  = (const float*)d_in[9];
  float* out = (float*)d_out;
  char* ws = (char*)d_ws;

  // workspace carve (bytes)
  u16*   xb   = (u16*)  (ws + 0);            // 38400*256*2   = 19,660,800
  u16*   wqkv = (u16*)  (ws + 19660800);     // 768*256*2     = 393,216
  float* bqkv = (float*)(ws + 20054016);     // 768*4         = 3,072
  u16*   qkv  = (u16*)  (ws + 20057088);     // 38400*768*2   = 58,982,400
  float* hbuf = (float*)(ws + 79039488);     // 38400*256*4   = 39,321,600  -> ends 118,361,088

  cast_x_kernel<<<4800, 256, 0, stream>>>(x, xb, 9830400/8);
  prep_w_kernel<<<192, 256, 0, stream>>>(Wq, Wk, Wv, bq, bk, bv, wqkv, bqkv);
  gemm_qkv_kernel<<<1800, 256, 0, stream>>>(xb, wqkv, bqkv, qkv);
  attn_kernel<<<768, 256, 0, stream>>>(qkv, adj, hbuf);
  resid_ln_kernel<<<9600, 256, 0, stream>>>(hbuf, x, gamma, beta, out);
}